// Round 5
// baseline (136.312 us; speedup 1.0000x reference)
//
#include <hip/hip_runtime.h>
#include <math.h>

#define K 3
#define K2 9
#define BB 4
#define C 64
#define H 128
#define W 128
#define O 64
#define HW (H*W)
#define Ho 128
#define Wo 128
#define TILE 64        // pixels per block (along w)

typedef _Float16 half4v __attribute__((ext_vector_type(4)));
typedef _Float16 half8v __attribute__((ext_vector_type(8)));
typedef float float4v __attribute__((ext_vector_type(4)));

__device__ __forceinline__ half8v bcast8(_Float16 w) {
    half8v v = {w, w, w, w, w, w, w, w};
    return v;
}

#define MFMA16(a, b, c) __builtin_amdgcn_mfma_f32_16x16x32_f16((a), (b), (c), 0, 0, 0)

// ---------------------------------------------------------------------------
// prep_all: blocks [0, BB*H) build xh (NCHW fp32 -> NHWC fp16, LDS transpose);
// blocks [BB*H, BB*H+144) pack MFMA B-fragments, TAP-MAJOR K: k = tap*64 + ch.
//  wB : [tap*2+s][q=o-tile(4)][lane(64)][jj(8)], ch = s*32+(lane>>4)*8+jj
//  wAB: [tap*2+s][jt=n-tile(2)][lane(64)][jj(8)], n = jt*16+(lane&15) in 0..26
// ---------------------------------------------------------------------------
__global__ __launch_bounds__(256) void prep_all(
    const float* __restrict__ x,
    const float* __restrict__ weight,
    const float* __restrict__ offset_w,
    const float* __restrict__ mod_w,
    _Float16* __restrict__ xh,
    _Float16* __restrict__ wB,
    _Float16* __restrict__ wAB)
{
    int t = threadIdx.x;
    if (blockIdx.x < BB * H) {
        __shared__ _Float16 tile[W][68];     // x-pos x channel (pad 68)
        int by = blockIdx.x;
        int y = by % H, b = by / H;
        int xq = t & 31, cr = t >> 5;        // xq: float4 index, cr: 0..7
        #pragma unroll
        for (int g = 0; g < 8; g++) {
            int c = g * 8 + cr;
            float4v v = *(const float4v*)&x[(((size_t)b * C + c) * H + y) * W + xq * 4];
            tile[xq * 4 + 0][c] = (_Float16)v[0];
            tile[xq * 4 + 1][c] = (_Float16)v[1];
            tile[xq * 4 + 2][c] = (_Float16)v[2];
            tile[xq * 4 + 3][c] = (_Float16)v[3];
        }
        __syncthreads();
        int xp2 = t >> 1, hf = t & 1;        // each thread writes 32 ch = 64 B
        const _Float16* src = &tile[xp2][hf * 32];
        _Float16* dst = xh + (((size_t)b * H + y) * W + xp2) * 64 + hf * 32;
        #pragma unroll
        for (int i = 0; i < 8; i++)
            *(half4v*)(dst + i * 4) = *(const half4v*)(src + i * 4);
    } else {
        int i = (blockIdx.x - BB * H) * 256 + t;
        if (i < K2 * 2 * 4 * 64 * 8) {          // 36864
            int jj = i & 7;
            int lane = (i >> 3) & 63;
            int q4 = (i >> 9) & 3;
            int i2 = i >> 11;                    // tap*2 + s, [0,18)
            int tap = i2 >> 1, s = i2 & 1;
            int ch = s * 32 + ((lane >> 4) & 3) * 8 + jj;
            int o = q4 * 16 + (lane & 15);
            wB[i] = (_Float16)weight[(o * C + ch) * 9 + tap];
        }
        if (i < K2 * 2 * 2 * 64 * 8) {          // 18432
            int jj = i & 7;
            int lane = (i >> 3) & 63;
            int jt = (i >> 9) & 1;
            int i2 = i >> 10;                    // tap*2 + s
            int tap = i2 >> 1, s = i2 & 1;
            int ch = s * 32 + ((lane >> 4) & 3) * 8 + jj;
            int n = jt * 16 + (lane & 15);
            float wv = 0.f;
            if (n < 27)
                wv = (n < 18) ? offset_w[(n * C + ch) * 9 + tap]
                              : mod_w[((n - 18) * C + ch) * 9 + tap];
            wAB[i] = (_Float16)wv;
        }
    }
}

// ---------------------------------------------------------------------------
// fused_kernel: one block per (b,h,64px strip), 256 threads, 4 waves.
// GATHER-MAPPING == MFMA-FRAGMENT-MAPPING: wave q owns px rows q*16+m16 and
// computes all 4 o-tiles. Lane (m16,quad) consumes A-fragment chunks
// {quad, 4+quad} of its OWN pixel, so that lane gathers exactly those 4-corner
// chunks and combines them straight into af0/af1 registers:
//   - no LDS A-tile, no cross-wave coupling -> ZERO barriers in phases A & C
//     (3 barriers/block total, was ~14);
//   - live set ~8 transient half8 + 16 acc ~= 55 VGPR -> no spill risk (the
//     rounds-1-3 failure was 105-VGPR ping-pong vs 64-VGPR allocation);
//   - wB slab (8 KB/tap) is shared by all 16 waves/CU -> L1-resident.
// All fp16 combine expressions and MFMA accumulation order are bit-identical
// to round 4 -> absmax unchanged.
// ---------------------------------------------------------------------------
__global__ __launch_bounds__(256, 4) void fused_kernel(
    const _Float16* __restrict__ xh,
    const _Float16* __restrict__ wB,
    const _Float16* __restrict__ wAB,
    const float* __restrict__ bias,
    const float* __restrict__ offset_b,
    const float* __restrict__ mod_b,
    float* __restrict__ out)
{
    __shared__ float s_out[64 * 65];            // 16,640 B (epilogue)
    __shared__ float s_res[27 * 65];            //  7,020 B (phase A out)
    __shared__ unsigned int s_ai[K2 * TILE];    //  2,304 B (a00 | dx<<14 | dy<<15)
    __shared__ half4v s_wgt[K2 * TILE];         //  4,608 B (fp16 corner products)
    __shared__ float s_mm[TILE];                //    256 B

    // XCD-aware swizzle: each XCD gets a contiguous 64-row h-band of one image.
    int blk = blockIdx.x;
    int xcd = blk & 7, idx = blk >> 3;
    int b  = xcd >> 1;
    int h  = ((xcd & 1) << 6) | (idx >> 1);
    int wt = idx & 1;
    int t  = threadIdx.x;
    int q  = t >> 6;                            // wave index
    int lane = t & 63;
    int m16 = lane & 15;
    int quad = (lane >> 4) & 3;
    int w0 = wt * TILE;
    int pw = q * 16 + m16;                      // this lane's owned pixel (in tile)

    const _Float16* xb = xh + (size_t)b * HW * 64;
    const _Float16* xbq = xb + quad * 8;        // lane's 16B chunk base (chunk quad)

    // ========== phase A: offset/mod conv — direct loads, NO barriers ========
    float4v acc2[2];
    {
        float4v z = {0.f, 0.f, 0.f, 0.f};
        acc2[0] = z; acc2[1] = z;
    }
    #pragma unroll
    for (int tap = 0; tap < K2; tap++) {
        const int ki = tap / 3, kj = tap % 3;
        int y = h + ki - 1;
        int xv = w0 + pw + kj - 1;
        _Float16 mk = (_Float16)((y >= 0 && y < H && xv >= 0 && xv < W) ? 1.f : 0.f);
        int yc = min(max(y, 0), H - 1);
        int xc = min(max(xv, 0), W - 1);
        const _Float16* src = xbq + ((size_t)(yc * W + xc)) * 64;
        half8v a0 = *(const half8v*)(src);
        half8v a1 = *(const half8v*)(src + 32);
        const _Float16* wp = wAB + (size_t)tap * 2048 + lane * 8;
        half8v af0 = a0 * bcast8(mk);
        acc2[0] = MFMA16(af0, *(const half8v*)(wp +    0), acc2[0]);
        acc2[1] = MFMA16(af0, *(const half8v*)(wp +  512), acc2[1]);
        half8v af1 = a1 * bcast8(mk);
        acc2[0] = MFMA16(af1, *(const half8v*)(wp + 1024), acc2[0]);
        acc2[1] = MFMA16(af1, *(const half8v*)(wp + 1536), acc2[1]);
    }

    // C layout: col(n)=m16, row(px-in-wave-tile)=quad*4+reg; wave q owns px tile q
    #pragma unroll
    for (int jt = 0; jt < 2; jt++) {
        int n = jt * 16 + m16;
        if (n < 27) {
            #pragma unroll
            for (int r = 0; r < 4; r++)
                s_res[n * 65 + q * 16 + quad * 4 + r] = acc2[jt][r];
        }
    }
    __syncthreads();                            // B1

    // ================= phase B: bilinear params + modmean =================
    #pragma unroll
    for (int ee = 0; ee < 3; ee++) {
        int e = t + ee * 256;
        if (e < K2 * TILE) {
            int k = e >> 6, p = e & 63;
            float offy = s_res[k * 65 + p] + offset_b[k];
            float offx = s_res[(9 + k) * 65 + p] + offset_b[9 + k];
            float sy = (float)(h + k / 3 - 1) + offy;
            float sx = (float)(w0 + p + k % 3 - 1) + offx;
            float fy = floorf(sy), fx = floorf(sx);
            int y0 = (int)fy, x0 = (int)fx;
            float wy1 = sy - fy, wx1 = sx - fx;
            int y0c = min(max(y0, 0), H - 1), y1c = min(max(y0 + 1, 0), H - 1);
            int x0c = min(max(x0, 0), W - 1), x1c = min(max(x0 + 1, 0), W - 1);
            s_ai[e] = (unsigned int)(y0c * W + x0c)
                    | ((unsigned int)(x1c - x0c) << 14)
                    | ((unsigned int)(y1c - y0c) << 15);
            float wg0 = (1.f - wy1) * ((y0 >= 0 && y0 < H) ? 1.f : 0.f);
            float wg1 = wy1 * ((y0 + 1 >= 0 && y0 + 1 < H) ? 1.f : 0.f);
            float wg2 = (1.f - wx1) * ((x0 >= 0 && x0 < W) ? 1.f : 0.f);
            float wg3 = wx1 * ((x0 + 1 >= 0 && x0 + 1 < W) ? 1.f : 0.f);
            half4v wp4;
            wp4[0] = (_Float16)(wg0 * wg2);   // (y0,x0)
            wp4[1] = (_Float16)(wg0 * wg3);   // (y0,x1)
            wp4[2] = (_Float16)(wg1 * wg2);   // (y1,x0)
            wp4[3] = (_Float16)(wg1 * wg3);   // (y1,x1)
            s_wgt[e] = wp4;
        }
    }
    if (t < TILE) {
        float sm = 0.f;
        #pragma unroll
        for (int m = 0; m < 9; m++) {
            float z = s_res[(18 + m) * 65 + t] + mod_b[m];
            sm += 1.f / (1.f + expf(-z));
        }
        s_mm[t] = sm * (1.f / 9.f);
    }
    __syncthreads();                            // B2

    // ====== phase C: deform gather straight to registers, NO barriers =======
    float4v acc[4];
    {
        float4v z = {0.f, 0.f, 0.f, 0.f};
        acc[0] = z; acc[1] = z; acc[2] = z; acc[3] = z;
    }
    #pragma unroll
    for (int tap = 0; tap < K2; tap++) {
        int e = tap * 64 + pw;
        unsigned int ai = s_ai[e];              // LDS broadcast across quads
        half4v wg = s_wgt[e];
        int a00 = ai & 0x3FFF;
        int dxo = ((ai >> 14) & 1) << 6;        // dx * 64 halves
        int dyo = ((ai >> 15) & 1) << 13;       // dy * W*64 halves
        const _Float16* base = xbq + (size_t)a00 * 64;
        half8v p00 = *(const half8v*)(base);
        half8v p01 = *(const half8v*)(base + dxo);
        half8v p10 = *(const half8v*)(base + dyo);
        half8v p11 = *(const half8v*)(base + dyo + dxo);
        half8v q00 = *(const half8v*)(base + 32);
        half8v q01 = *(const half8v*)(base + 32 + dxo);
        half8v q10 = *(const half8v*)(base + 32 + dyo);
        half8v q11 = *(const half8v*)(base + 32 + dyo + dxo);
        const _Float16* wp = wB + (size_t)tap * 4096 + lane * 8;
        half8v af0 = p00 * bcast8(wg[0]) + p01 * bcast8(wg[1])
                   + p10 * bcast8(wg[2]) + p11 * bcast8(wg[3]);
        acc[0] = MFMA16(af0, *(const half8v*)(wp +    0), acc[0]);
        acc[1] = MFMA16(af0, *(const half8v*)(wp +  512), acc[1]);
        acc[2] = MFMA16(af0, *(const half8v*)(wp + 1024), acc[2]);
        acc[3] = MFMA16(af0, *(const half8v*)(wp + 1536), acc[3]);
        half8v af1 = q00 * bcast8(wg[0]) + q01 * bcast8(wg[1])
                   + q10 * bcast8(wg[2]) + q11 * bcast8(wg[3]);
        acc[0] = MFMA16(af1, *(const half8v*)(wp + 2048), acc[0]);
        acc[1] = MFMA16(af1, *(const half8v*)(wp + 2560), acc[1]);
        acc[2] = MFMA16(af1, *(const half8v*)(wp + 3072), acc[2]);
        acc[3] = MFMA16(af1, *(const half8v*)(wp + 3584), acc[3]);
    }

    // ================= epilogue =================
    // acc[i]: col(m16) = o within o-tile i, row(quad*4+r) = px within wave tile
    #pragma unroll
    for (int i = 0; i < 4; i++) {
        #pragma unroll
        for (int r = 0; r < 4; r++)
            s_out[(i * 16 + m16) * 65 + q * 16 + quad * 4 + r] = acc[i][r];
    }
    __syncthreads();                            // B3
    {
        float mm = s_mm[lane];
        #pragma unroll
        for (int jj = 0; jj < 16; jj++) {
            int o = q * 16 + jj;
            out[(((size_t)b * O + o) * Ho + h) * Wo + w0 + lane] =
                s_out[o * 65 + lane] * mm + bias[o];
        }
    }
}

extern "C" void kernel_launch(void* const* d_in, const int* in_sizes, int n_in,
                              void* d_out, int out_size, void* d_ws, size_t ws_size,
                              hipStream_t stream) {
    const float* x        = (const float*)d_in[0];
    const float* weight   = (const float*)d_in[1];
    const float* bias     = (const float*)d_in[2];
    const float* offset_w = (const float*)d_in[3];
    const float* offset_b = (const float*)d_in[4];
    const float* mod_w    = (const float*)d_in[5];
    const float* mod_b    = (const float*)d_in[6];
    float* out = (float*)d_out;

    // Workspace (halves): wB 36,864 | wAB 18,432 | xh 4,194,304 (byte 110,592, 16B-aligned)
    _Float16* wB  = (_Float16*)d_ws;
    _Float16* wAB = wB + 36864;
    _Float16* xh  = wAB + 18432;

    prep_all<<<BB * H + 144, 256, 0, stream>>>(
        x, weight, offset_w, mod_w, xh, wB, wAB);

    int nblk = BB * Ho * (Wo / TILE);   // 1024
    fused_kernel<<<nblk, 256, 0, stream>>>(
        xh, wB, wAB, bias, offset_b, mod_b, out);
}

// Round 6
// 107.408 us; speedup vs baseline: 1.2691x; 1.2691x over previous
//
#include <hip/hip_runtime.h>
#include <math.h>

#define K 3
#define K2 9
#define BB 4
#define C 64
#define H 128
#define W 128
#define O 64
#define HW (H*W)
#define Ho 128
#define Wo 128
#define TILE 64        // pixels per block (along w)

typedef _Float16 half4v __attribute__((ext_vector_type(4)));
typedef _Float16 half8v __attribute__((ext_vector_type(8)));
typedef float float4v __attribute__((ext_vector_type(4)));

__device__ __forceinline__ half8v bcast8(_Float16 w) {
    half8v v = {w, w, w, w, w, w, w, w};
    return v;
}

#define MFMA16(a, b, c) __builtin_amdgcn_mfma_f32_16x16x32_f16((a), (b), (c), 0, 0, 0)
#define SB() __builtin_amdgcn_sched_barrier(0)

// ---------------------------------------------------------------------------
// prep_all: blocks [0, BB*H) build xh (NCHW fp32 -> NHWC fp16, LDS transpose);
// blocks [BB*H, BB*H+144) pack MFMA B-fragments, TAP-MAJOR K: k = tap*64 + ch.
//  wB : [tap*2+s][q=o-tile(4)][lane(64)][jj(8)], ch = s*32+(lane>>4)*8+jj
//  wAB: [tap*2+s][jt=n-tile(2)][lane(64)][jj(8)], n = jt*16+(lane&15) in 0..26
// ---------------------------------------------------------------------------
__global__ __launch_bounds__(256) void prep_all(
    const float* __restrict__ x,
    const float* __restrict__ weight,
    const float* __restrict__ offset_w,
    const float* __restrict__ mod_w,
    _Float16* __restrict__ xh,
    _Float16* __restrict__ wB,
    _Float16* __restrict__ wAB)
{
    int t = threadIdx.x;
    if (blockIdx.x < BB * H) {
        __shared__ _Float16 tile[W][68];     // x-pos x channel (pad 68)
        int by = blockIdx.x;
        int y = by % H, b = by / H;
        int xq = t & 31, cr = t >> 5;        // xq: float4 index, cr: 0..7
        #pragma unroll
        for (int g = 0; g < 8; g++) {
            int c = g * 8 + cr;
            float4v v = *(const float4v*)&x[(((size_t)b * C + c) * H + y) * W + xq * 4];
            tile[xq * 4 + 0][c] = (_Float16)v[0];
            tile[xq * 4 + 1][c] = (_Float16)v[1];
            tile[xq * 4 + 2][c] = (_Float16)v[2];
            tile[xq * 4 + 3][c] = (_Float16)v[3];
        }
        __syncthreads();
        int xp2 = t >> 1, hf = t & 1;        // each thread writes 32 ch = 64 B
        const _Float16* src = &tile[xp2][hf * 32];
        _Float16* dst = xh + (((size_t)b * H + y) * W + xp2) * 64 + hf * 32;
        #pragma unroll
        for (int i = 0; i < 8; i++)
            *(half4v*)(dst + i * 4) = *(const half4v*)(src + i * 4);
    } else {
        int i = (blockIdx.x - BB * H) * 256 + t;
        if (i < K2 * 2 * 4 * 64 * 8) {          // 36864
            int jj = i & 7;
            int lane = (i >> 3) & 63;
            int q4 = (i >> 9) & 3;
            int i2 = i >> 11;                    // tap*2 + s, [0,18)
            int tap = i2 >> 1, s = i2 & 1;
            int ch = s * 32 + ((lane >> 4) & 3) * 8 + jj;
            int o = q4 * 16 + (lane & 15);
            wB[i] = (_Float16)weight[(o * C + ch) * 9 + tap];
        }
        if (i < K2 * 2 * 2 * 64 * 8) {          // 18432
            int jj = i & 7;
            int lane = (i >> 3) & 63;
            int jt = (i >> 9) & 1;
            int i2 = i >> 10;                    // tap*2 + s
            int tap = i2 >> 1, s = i2 & 1;
            int ch = s * 32 + ((lane >> 4) & 3) * 8 + jj;
            int n = jt * 16 + (lane & 15);
            float wv = 0.f;
            if (n < 27)
                wv = (n < 18) ? offset_w[(n * C + ch) * 9 + tap]
                              : mod_w[((n - 18) * C + ch) * 9 + tap];
            wAB[i] = (_Float16)wv;
        }
    }
}

// ---------------------------------------------------------------------------
// fused_kernel: one block per (b,h,64px strip), 256 threads, 4 waves.
// Round-4 cooperative structure (best measured), with phase C re-pipelined to
// PREFETCH DISTANCE 2: steady state per tap is
//   { store G(t+1) [loads issued last iter] -> issue G(t+2) -> MFMA(t) -> bar }
// so in-flight gather loads survive across MFMA + barrier + next-iter addr
// calc (~250-400 cyc hide window) instead of only the 8-MFMA cluster
// (~40-80 cyc). Register pressure unchanged: exactly one 8x half8v group in
// flight (store frees the regs the new issue reuses). Stores target
// buf[(t+1)&1], reads buf[t&1], single barrier per tap separates cross-wave
// reuse — correctness identical to round 4; fp16 math order bit-identical.
// ---------------------------------------------------------------------------
__global__ __launch_bounds__(256) void fused_kernel(
    const _Float16* __restrict__ xh,
    const _Float16* __restrict__ wB,
    const _Float16* __restrict__ wAB,
    const float* __restrict__ bias,
    const float* __restrict__ offset_b,
    const float* __restrict__ mod_b,
    float* __restrict__ out)
{
    __shared__ __align__(16) unsigned char s_big[25344]; // s_rows[3][66][64]h | s_T[2][64][64]h | s_out[64][65]f
    __shared__ float s_res[27 * 65];            //  7,020 B (phase A out, separate: no barrier before write)
    __shared__ unsigned int s_ai[K2 * TILE];    //  2,304 B (a00 | dx<<14 | dy<<15)
    __shared__ half4v s_wgt[K2 * TILE];         //  4,608 B (fp16 corner products)
    __shared__ float s_mm[TILE];                //    256 B
    char* s_rowsB = (char*)s_big;               // phase A input rows (swizzled)
    char* s_TB    = (char*)s_big;               // phase C A-tiles (swizzled, dbuf)
    float* s_out  = (float*)s_big;              // epilogue [64][65]

    // XCD-aware swizzle: each XCD gets a contiguous 64-row h-band of one image.
    int blk = blockIdx.x;
    int xcd = blk & 7, idx = blk >> 3;
    int b  = xcd >> 1;
    int h  = ((xcd & 1) << 6) | (idx >> 1);
    int wt = idx & 1;
    int t  = threadIdx.x;
    int q  = t >> 6;                            // wave index
    int lane = t & 63;
    int m16 = lane & 15;
    int quad = (lane >> 4) & 3;
    int w0 = wt * TILE;
    int pw = q * 16 + m16;                      // wave-local pixel row for phase A
    int gpx0 = q * 16 + (lane >> 3);            // cooperative gather: pixel (pg=0)
    int seg  = lane & 7;                        // 16B channel segment

    const _Float16* xb = xh + (size_t)b * HW * 64;

    // ======== phase A stage: rows h-1..h+1 x 66 px, zero-masked, swizzled ===
    #pragma unroll
    for (int it = 0; it < 7; it++) {
        int e = t + it * 256;
        if (e < 3 * 66 * 8) {                   // 1584 16B chunks
            int sg = e & 7;
            int pr = e >> 3;                    // 0..197
            int yr = pr / 66;
            int px66 = pr - yr * 66;
            int y = h + yr - 1;
            int xv = w0 + px66 - 1;
            _Float16 mk = (_Float16)((y >= 0 && y < H && xv >= 0 && xv < W) ? 1.f : 0.f);
            int yc = min(max(y, 0), H - 1);
            int xc = min(max(xv, 0), W - 1);
            half8v v = *(const half8v*)(xb + ((size_t)(yc * W + xc)) * 64 + sg * 8);
            *(half8v*)(s_rowsB + (yr * 66 + px66) * 128 + ((sg * 16) ^ ((px66 & 7) << 4))) = v * bcast8(mk);
        }
    }
    __syncthreads();

    // ======== phase A compute: 9 taps, no barriers, ds_read + MFMA ==========
    float4v acc2[2];
    {
        float4v z = {0.f, 0.f, 0.f, 0.f};
        acc2[0] = z; acc2[1] = z;
    }

#define COMPA(tap) { \
    const int ki = (tap) / 3, kj = (tap) % 3; \
    int px66 = pw + kj; \
    const char* rbase = s_rowsB + (ki * 66 + px66) * 128; \
    int swz = (px66 & 7) << 4; \
    const _Float16* wp = wAB + (size_t)(tap) * 2048 + lane * 8; \
    half8v af0 = *(const half8v*)(rbase + ((quad * 16) ^ swz)); \
    acc2[0] = MFMA16(af0, *(const half8v*)(wp +    0), acc2[0]); \
    acc2[1] = MFMA16(af0, *(const half8v*)(wp +  512), acc2[1]); \
    half8v af1 = *(const half8v*)(rbase + ((64 + quad * 16) ^ swz)); \
    acc2[0] = MFMA16(af1, *(const half8v*)(wp + 1024), acc2[0]); \
    acc2[1] = MFMA16(af1, *(const half8v*)(wp + 1536), acc2[1]); \
}
    COMPA(0); COMPA(1); COMPA(2);
    COMPA(3); COMPA(4); COMPA(5);
    COMPA(6); COMPA(7); COMPA(8);

    // C layout: col(n)=m16, row(px-in-wave-tile)=quad*4+reg; wave q owns px tile q
    #pragma unroll
    for (int jt = 0; jt < 2; jt++) {
        int n = jt * 16 + m16;
        if (n < 27) {
            #pragma unroll
            for (int r = 0; r < 4; r++)
                s_res[n * 65 + q * 16 + quad * 4 + r] = acc2[jt][r];
        }
    }
    __syncthreads();

    // ================= phase B: bilinear params + modmean =================
    #pragma unroll
    for (int ee = 0; ee < 3; ee++) {
        int e = t + ee * 256;
        if (e < K2 * TILE) {
            int k = e >> 6, p = e & 63;
            float offy = s_res[k * 65 + p] + offset_b[k];
            float offx = s_res[(9 + k) * 65 + p] + offset_b[9 + k];
            float sy = (float)(h + k / 3 - 1) + offy;
            float sx = (float)(w0 + p + k % 3 - 1) + offx;
            float fy = floorf(sy), fx = floorf(sx);
            int y0 = (int)fy, x0 = (int)fx;
            float wy1 = sy - fy, wx1 = sx - fx;
            int y0c = min(max(y0, 0), H - 1), y1c = min(max(y0 + 1, 0), H - 1);
            int x0c = min(max(x0, 0), W - 1), x1c = min(max(x0 + 1, 0), W - 1);
            s_ai[e] = (unsigned int)(y0c * W + x0c)
                    | ((unsigned int)(x1c - x0c) << 14)
                    | ((unsigned int)(y1c - y0c) << 15);
            float wg0 = (1.f - wy1) * ((y0 >= 0 && y0 < H) ? 1.f : 0.f);
            float wg1 = wy1 * ((y0 + 1 >= 0 && y0 + 1 < H) ? 1.f : 0.f);
            float wg2 = (1.f - wx1) * ((x0 >= 0 && x0 < W) ? 1.f : 0.f);
            float wg3 = wx1 * ((x0 + 1 >= 0 && x0 + 1 < W) ? 1.f : 0.f);
            half4v wp4;
            wp4[0] = (_Float16)(wg0 * wg2);   // (y0,x0)
            wp4[1] = (_Float16)(wg0 * wg3);   // (y0,x1)
            wp4[2] = (_Float16)(wg1 * wg2);   // (y1,x0)
            wp4[3] = (_Float16)(wg1 * wg3);   // (y1,x1)
            s_wgt[e] = wp4;
        }
    }
    if (t < TILE) {
        float sm = 0.f;
        #pragma unroll
        for (int m = 0; m < 9; m++) {
            float z = s_res[(18 + m) * 65 + t] + mod_b[m];
            sm += 1.f / (1.f + expf(-z));
        }
        s_mm[t] = sm * (1.f / 9.f);
    }
    __syncthreads();

    // ====== phase C: deform gather + main MFMA (prefetch-distance-2) ========
    float4v acc[4];
    {
        float4v z = {0.f, 0.f, 0.f, 0.f};
        acc[0] = z; acc[1] = z; acc[2] = z; acc[3] = z;
    }

#define GATHER_LOAD(tapn, pg) { \
    int e = (tapn) * 64 + gpx0 + (pg) * 8; \
    unsigned int ai = s_ai[e]; \
    wgp##pg = s_wgt[e]; \
    int a00 = ai & 0x3FFF; \
    int dxo = ((ai >> 14) & 1) << 6;          /* dx * 64 halves   */ \
    int dyo = ((ai >> 15) & 1) << 13;         /* dy * W*64 halves */ \
    const _Float16* base = xb + (size_t)a00 * 64 + seg * 8; \
    r##pg##0 = *(const half8v*)(base); \
    r##pg##1 = *(const half8v*)(base + dxo); \
    r##pg##2 = *(const half8v*)(base + dyo); \
    r##pg##3 = *(const half8v*)(base + dyo + dxo); \
}
#define GATHER_STORE(buf, pg) { \
    int ppx = gpx0 + (pg) * 8; \
    half8v v = r##pg##0 * bcast8(wgp##pg[0]) + r##pg##1 * bcast8(wgp##pg[1]) \
             + r##pg##2 * bcast8(wgp##pg[2]) + r##pg##3 * bcast8(wgp##pg[3]); \
    *(half8v*)(s_TB + ((buf) * 64 + ppx) * 128 + ((seg * 16) ^ ((ppx & 7) << 4))) = v; \
}

    // carried in-flight gather group (exactly one group live at a time)
    half8v r00, r01, r02, r03, r10, r11, r12, r13;
    half4v wgp0, wgp1;

    // prologue: store G(0) -> buf0, leave G(1) in flight
    GATHER_LOAD(0, 0); GATHER_LOAD(0, 1);       // issue G(0)
    GATHER_STORE(0, 0); GATHER_STORE(0, 1);     // wait + combine + store G(0)
    GATHER_LOAD(1, 0); GATHER_LOAD(1, 1);       // issue G(1) (in flight)
    __syncthreads();

    #pragma unroll 1
    for (int tap = 0; tap < K2; tap++) {
        int buf = tap & 1;
        if (tap < 8) {                           // store G(tap+1) (issued last iter)
            GATHER_STORE(buf ^ 1, 0); GATHER_STORE(buf ^ 1, 1);
        }
        if (tap < 7) {                           // issue G(tap+2), stays in flight
            GATHER_LOAD(tap + 2, 0); GATHER_LOAD(tap + 2, 1);
        }
        SB();                                    // pin: issues stay before MFMAs
        {
            const _Float16* wp = wB + (size_t)tap * 4096 + q * 512 + lane * 8;
            int swzT = (m16 & 7) << 4;
            const char* tb = s_TB + (buf * 64 + m16) * 128;
            #pragma unroll
            for (int s = 0; s < 2; s++) {
                half8v bf = *(const half8v*)(wp + s * 2048);
                #pragma unroll
                for (int i = 0; i < 4; i++) {
                    half8v af = *(const half8v*)(tb + i * 16 * 128 + ((s * 64 + quad * 16) ^ swzT));
                    acc[i] = MFMA16(af, bf, acc[i]);
                }
            }
        }
        __syncthreads();
    }

    // ================= epilogue =================
    // acc[i]: col(m16) = o within o-tile... o = q*16+m16; row = i*16+quad*4+r
    #pragma unroll
    for (int i = 0; i < 4; i++) {
        int o = q * 16 + m16;
        #pragma unroll
        for (int r = 0; r < 4; r++)
            s_out[o * 65 + i * 16 + quad * 4 + r] = acc[i][r];
    }
    __syncthreads();
    {
        float mm = s_mm[lane];
        #pragma unroll
        for (int jj = 0; jj < 16; jj++) {
            int o = q * 16 + jj;
            out[(((size_t)b * O + o) * Ho + h) * Wo + w0 + lane] =
                s_out[o * 65 + lane] * mm + bias[o];
        }
    }
}

extern "C" void kernel_launch(void* const* d_in, const int* in_sizes, int n_in,
                              void* d_out, int out_size, void* d_ws, size_t ws_size,
                              hipStream_t stream) {
    const float* x        = (const float*)d_in[0];
    const float* weight   = (const float*)d_in[1];
    const float* bias     = (const float*)d_in[2];
    const float* offset_w = (const float*)d_in[3];
    const float* offset_b = (const float*)d_in[4];
    const float* mod_w    = (const float*)d_in[5];
    const float* mod_b    = (const float*)d_in[6];
    float* out = (float*)d_out;

    // Workspace (halves): wB 36,864 | wAB 18,432 | xh 4,194,304 (byte 110,592, 16B-aligned)
    _Float16* wB  = (_Float16*)d_ws;
    _Float16* wAB = wB + 36864;
    _Float16* xh  = wAB + 18432;

    prep_all<<<BB * H + 144, 256, 0, stream>>>(
        x, weight, offset_w, mod_w, xh, wB, wAB);

    int nblk = BB * Ho * (Wo / TILE);   // 1024
    fused_kernel<<<nblk, 256, 0, stream>>>(
        xh, wB, wAB, bias, offset_b, mod_b, out);
}